// Round 8
// baseline (701.309 us; speedup 1.0000x reference)
//
#include <hip/hip_runtime.h>
#include <hip/hip_bf16.h>

#define N_NODES   20000
#define N_EDGES   100000
#define N_REL     1000
#define F_DIM     128
#define N_HEAD    4
#define HC        512      // N_HEAD * F_DIM
#define HC2       256      // HC/2 (bf16 pairs)
#define N_LAYERS  4
#define REL_EXT_ROWS 1008  // 1000 relations + 1 mean row
#define NEG_SLOPE 0.2f
#define MAXE      256      // edge slots per softmax chunk

typedef __attribute__((ext_vector_type(8))) short short8;
typedef __attribute__((ext_vector_type(4))) float floatx4;

__device__ __forceinline__ float loadIn(const void* p, size_t i, int f32) {
    if (f32) return ((const float*)p)[i];
    union { unsigned int u; float f; } c;
    c.u = ((unsigned int)((const unsigned short*)p)[i]) << 16;
    return c.f;
}

__device__ __forceinline__ unsigned short f2bf(float v) {
    __hip_bfloat16 b = __float2bfloat16(v);
    return *(unsigned short*)&b;
}

__device__ __forceinline__ void unpack2(unsigned int u, float& lo, float& hi) {
    union { unsigned int u; float f; } a, b;
    a.u = u << 16;
    b.u = u & 0xFFFF0000u;
    lo = a.f; hi = b.f;
}

// ---------------- dtype detection ----------------
__global__ void detect_kernel(const unsigned short* __restrict__ x, int* __restrict__ flag) {
    int t = threadIdx.x;  // 64
    int cnt = 0;
    for (int j = t; j < 256; j += 64) {
        int e = (x[j] >> 7) & 0xFF;
        if (e >= 143) cnt++;
    }
    for (int off = 32; off; off >>= 1) cnt += __shfl_xor(cnt, off);
    if (t == 0) flag[0] = (cnt >= 8) ? 1 : 0;
}

// ---------------- preprocessing ----------------

__global__ void hist_kernel(const int* __restrict__ dst, const int* __restrict__ rel,
                            int* __restrict__ deg, int* __restrict__ rcount) {
    int e = blockIdx.x * 256 + threadIdx.x;
    if (e < N_EDGES) {
        atomicAdd(&deg[dst[e]], 1);
        atomicAdd(&rcount[rel[e]], 1);
    }
}

__global__ void ea_mean_kernel(const int* __restrict__ rcount,
                               const void* __restrict__ relations,
                               float* __restrict__ ea_mean, const int* __restrict__ flag) {
    int f32 = flag[0];
    int b = blockIdx.x;
    int t = threadIdx.x;
    int col = t & 127;
    int rhalf = t >> 7;
    float acc = 0.f;
    for (int j = 0; j < 4; ++j) {
        int r = b * 8 + j * 2 + rhalf;
        acc += (float)rcount[r] * loadIn(relations, (size_t)r * F_DIM + col, f32);
    }
    __shared__ float part[256];
    part[t] = acc;
    __syncthreads();
    if (t < 128)
        atomicAdd(&ea_mean[col], (part[t] + part[t + 128]) * (1.f / (float)N_EDGES));
}

__global__ void relext_kernel(const void* __restrict__ relations,
                              const float* __restrict__ ea_mean,
                              unsigned short* __restrict__ rel_ext, const int* __restrict__ flag) {
    int idx = blockIdx.x * 256 + threadIdx.x;
    if (idx >= REL_EXT_ROWS * F_DIM) return;
    int f32 = flag[0];
    int r = idx >> 7;
    int c = idx & 127;
    float v;
    if (r < N_REL)       v = loadIn(relations, idx, f32);
    else if (r == N_REL) v = ea_mean[c];
    else                 v = 0.f;
    rel_ext[idx] = f2bf(v);
}

__global__ void scan_kernel(const int* __restrict__ deg,
                            int* __restrict__ row_start, int* __restrict__ cursor) {
    __shared__ int part[1024];
    int t = threadIdx.x;
    const int CH = (N_NODES + 1023) / 1024;  // 20
    int base = t * CH;
    int sum = 0;
    for (int j = 0; j < CH; ++j) {
        int idx = base + j;
        if (idx < N_NODES) sum += deg[idx];
    }
    part[t] = sum;
    __syncthreads();
    for (int off = 1; off < 1024; off <<= 1) {
        int u = (t >= off) ? part[t - off] : 0;
        __syncthreads();
        part[t] += u;
        __syncthreads();
    }
    int run = part[t] - sum;
    for (int j = 0; j < CH; ++j) {
        int idx = base + j;
        if (idx < N_NODES) {
            row_start[idx] = run;
            cursor[idx] = run;
            run += deg[idx];
        }
    }
    if (t == 1023) row_start[N_NODES] = part[1023];
}

__global__ void scatter_kernel(const int* __restrict__ src, const int* __restrict__ dst,
                               const int* __restrict__ rel, int* __restrict__ cursor,
                               int* __restrict__ csr_pack) {
    int e = blockIdx.x * 256 + threadIdx.x;
    if (e < N_EDGES) {
        int d = dst[e];
        int p = atomicAdd(&cursor[d], 1);
        csr_pack[p] = src[e] | (rel[e] << 16);
    }
}

__global__ void tail_kernel(const void* __restrict__ relations, void* __restrict__ out,
                            const int* __restrict__ flag) {
    int i = blockIdx.x * 256 + threadIdx.x;
    if (i >= N_REL * F_DIM) return;
    int f32 = flag[0];
    float v = loadIn(relations, i, f32);
    size_t o = (size_t)N_NODES * F_DIM + i;
    if (f32) ((float*)out)[o] = v;
    else     ((unsigned short*)out)[o] = f2bf(v);
}

// ---------------- weight transpose: W[l][128 k][512 n] -> Wt[mat][512 n][128 k] bf16 ----------------
__global__ void w_transpose_kernel(const void* __restrict__ Wl, const void* __restrict__ Wr,
                                   const void* __restrict__ We,
                                   unsigned short* __restrict__ Wt, const int* __restrict__ flag) {
    int f32 = flag[0];
    int k0 = blockIdx.x * 64;
    int n0 = blockIdx.y * 64;
    int mat = blockIdx.z;
    const void* src = (mat < 4) ? Wl : (mat < 8 ? Wr : We);
    size_t base = (size_t)(mat & 3) * F_DIM * HC;
    unsigned short* dst = Wt + (size_t)mat * HC * F_DIM;
    __shared__ float T[64][65];
    int t = threadIdx.x;
    int r = t >> 2, cq = t & 3;
    for (int j = 0; j < 16; ++j) {
        int n = cq * 16 + j;
        T[n][r] = loadIn(src, base + (size_t)(k0 + r) * HC + n0 + n, f32);
    }
    __syncthreads();
    for (int j = 0; j < 16; ++j) {
        int k = cq * 16 + j;
        dst[(size_t)(n0 + r) * F_DIM + k0 + k] = f2bf(T[r][k]);
    }
}

// ---------------- projection GEMM (latency-optimized grid) ----------------
__launch_bounds__(256, 4)
__global__ void proj_kernel(const void* __restrict__ A, int a_input, int M,
                            const unsigned short* __restrict__ Wt0,
                            const unsigned short* __restrict__ Wt1,
                            const void* __restrict__ bias0, size_t b0_off,
                            const void* __restrict__ bias1, size_t b1_off,
                            unsigned short* __restrict__ out0,
                            unsigned short* __restrict__ out1,
                            int tpb, const int* __restrict__ flag) {
    __shared__ __align__(16) short As[64][136];    // 17.4 KB
    __shared__ __align__(16) short BtRaw[128 * 72];// 18.4 KB; Cs view: stride 136, 64 rows
    int f32 = flag[0];
    int a_f32 = a_input ? f32 : 0;
    int m0 = blockIdx.x * 64;
    int t = threadIdx.x;

    for (int j = 0; j < 4; ++j) {
        int c = t + j * 256;
        int row = c >> 4;
        int colc = (c & 15) * 8;
        int gm = m0 + row;
        short8 v = (short8){0, 0, 0, 0, 0, 0, 0, 0};
        if (gm < M) {
            size_t idx = (size_t)gm * F_DIM + colc;
            if (a_f32) {
                const float* Af = (const float*)A;
                for (int q = 0; q < 8; ++q) v[q] = (short)f2bf(Af[idx + q]);
            } else {
                v = *(const short8*)((const unsigned short*)A + idx);
            }
        }
        *(short8*)&As[row][colc] = v;
    }

    int wave = t >> 6, lane = t & 63;
    int wm = (wave >> 1) * 32, wn = (wave & 1) * 64;
    int r16 = lane & 15, quad = lane >> 4;

    for (int it = 0; it < tpb; ++it) {
        int nt = blockIdx.y * tpb + it;
        const unsigned short* Wt = (nt < 4) ? Wt0 : Wt1;
        int n0 = (nt & 3) * 128;

        floatx4 acc[2][4];
        for (int mi = 0; mi < 2; ++mi)
            for (int ni = 0; ni < 4; ++ni)
                acc[mi][ni] = (floatx4){0.f, 0.f, 0.f, 0.f};

        for (int half = 0; half < 2; ++half) {
            __syncthreads();
            for (int j = 0; j < 4; ++j) {
                int c = t + j * 256;
                int nl = c >> 3;
                int kc = (c & 7) * 8;
                *(short8*)&BtRaw[nl * 72 + kc] =
                    *(const short8*)(Wt + (size_t)(n0 + nl) * F_DIM + half * 64 + kc);
            }
            __syncthreads();

            for (int kk = 0; kk < 2; ++kk) {
                short8 a[2], b[4];
                for (int mi = 0; mi < 2; ++mi)
                    a[mi] = *(const short8*)&As[wm + mi * 16 + r16][half * 64 + kk * 32 + quad * 8];
                for (int ni = 0; ni < 4; ++ni)
                    b[ni] = *(const short8*)&BtRaw[(wn + ni * 16 + r16) * 72 + kk * 32 + quad * 8];
                for (int mi = 0; mi < 2; ++mi)
                    for (int ni = 0; ni < 4; ++ni)
                        acc[mi][ni] = __builtin_amdgcn_mfma_f32_16x16x32_bf16(a[mi], b[ni], acc[mi][ni], 0, 0, 0);
            }
        }

        const void* bias = (nt < 4) ? bias0 : bias1;
        size_t boff = (nt < 4) ? b0_off : b1_off;
        unsigned short* out = (nt < 4) ? out0 : out1;
        __syncthreads();
        for (int mi = 0; mi < 2; ++mi) {
            for (int ni = 0; ni < 4; ++ni) {
                int col = wn + ni * 16 + r16;
                float bv = bias ? loadIn(bias, boff + n0 + col, f32) : 0.f;
                for (int r = 0; r < 4; ++r) {
                    int rowl = wm + mi * 16 + quad * 4 + r;
                    BtRaw[rowl * 136 + col] = (short)f2bf(acc[mi][ni][r] + bv);
                }
            }
        }
        __syncthreads();
        for (int j = 0; j < 4; ++j) {
            int c = t + j * 256;
            int rowl = c >> 4;
            int colc = (c & 15) * 8;
            int gm = m0 + rowl;
            if (gm < M)
                *(short8*)(out + (size_t)gm * HC + n0 + colc) =
                    *(const short8*)&BtRaw[rowl * 136 + colc];
        }
    }
}

// ---------------- edge kernel: edge-parallel chunked softmax ----------------
// One block per dst node; each wave covers the FULL 512-ch row (lane = 8 contiguous
// channels, head = lane>>4) and handles edge slots  slot % 4 == wave.
// Slot 0 = self-loop (mean edge-attr). Per chunk (<=256 slots):
//   A: logits -> LDS (16-lane reduce), B: chunk softmax + online merge, C: weighted gather.
__launch_bounds__(256)
__global__ void edge_kernel(const unsigned int* __restrict__ xl2,
                            const unsigned int* __restrict__ xr2,
                            const unsigned int* __restrict__ re2,
                            const int* __restrict__ row_start,
                            const int* __restrict__ csr_pack,
                            const void* __restrict__ att, size_t att_off,
                            const void* __restrict__ bias, size_t bias_off,
                            void* __restrict__ hout, int final_layer,
                            const int* __restrict__ flag) {
    __shared__ float l_log[N_HEAD][MAXE];   // logits, then p=exp(logit-m)*fc
    __shared__ float l_acc[N_HEAD][HC / N_HEAD * N_HEAD];  // [4][512] per-wave partials
    __shared__ float s_run[N_HEAD], m_run[N_HEAD], chunk_sc[N_HEAD];

    int f32 = flag[0];
    int i = blockIdx.x;
    int t = threadIdx.x;
    int w = t >> 6, lane = t & 63;
    int hl = lane >> 4;          // head of this lane's channels

    const uint4* xl4 = (const uint4*)xl2;
    const uint4* re4 = (const uint4*)re2;
    const uint4* xr4 = (const uint4*)xr2;

    // per-lane row data: channels [lane*8, lane*8+8)
    float xrv[8], attv[8];
    {
        uint4 u = xr4[(size_t)i * 64 + lane];
        unpack2(u.x, xrv[0], xrv[1]); unpack2(u.y, xrv[2], xrv[3]);
        unpack2(u.z, xrv[4], xrv[5]); unpack2(u.w, xrv[6], xrv[7]);
        for (int q = 0; q < 8; ++q)
            attv[q] = loadIn(att, att_off + lane * 8 + q, f32);
    }

    if (t < N_HEAD) { s_run[t] = 0.f; m_run[t] = -3.0e38f; }

    int e0 = row_start[i], e1 = row_start[i + 1];
    if (e0 < 0) e0 = 0;
    if (e1 > N_EDGES) e1 = N_EDGES;
    if (e1 < e0) e1 = e0;
    int total = (e1 - e0) + 1;                 // + self-loop
    int nchunks = (total + MAXE - 1) / MAXE;

    float acc[8];
    for (int q = 0; q < 8; ++q) acc[q] = 0.f;

    for (int ck = 0; ck < nchunks; ++ck) {
        int start = ck * MAXE;
        int cnt = total - start; if (cnt > MAXE) cnt = MAXE;
        __syncthreads();   // l_log free for reuse (phase C of prev chunk done)

        // ---- phase A: logits ----
        for (int slot = w; slot < cnt; slot += 4) {
            int gs = start + slot;
            int src, rr;
            if (gs == 0) { src = i; rr = N_REL; }
            else {
                int pk = csr_pack[e0 + gs - 1];
                src = pk & 0xFFFF;            if (src >= N_NODES) src = 0;
                rr  = (pk >> 16) & 0x3FF;     if (rr > N_REL) rr = N_REL;
            }
            uint4 xu = xl4[(size_t)src * 64 + lane];
            uint4 ru = re4[(size_t)rr * 64 + lane];
            float xv[8], rv[8];
            unpack2(xu.x, xv[0], xv[1]); unpack2(xu.y, xv[2], xv[3]);
            unpack2(xu.z, xv[4], xv[5]); unpack2(xu.w, xv[6], xv[7]);
            unpack2(ru.x, rv[0], rv[1]); unpack2(ru.y, rv[2], rv[3]);
            unpack2(ru.z, rv[4], rv[5]); unpack2(ru.w, rv[6], rv[7]);
            float part = 0.f;
            for (int q = 0; q < 8; ++q) {
                float u = xv[q] + xrv[q] + rv[q];
                u = (u > 0.f) ? u : NEG_SLOPE * u;
                part += u * attv[q];
            }
            for (int off = 8; off; off >>= 1) part += __shfl_xor(part, off);
            if ((lane & 15) == 0) l_log[hl][slot] = part;
        }
        __syncthreads();

        // ---- phase B: chunk softmax (wave w handles head w) + online merge ----
        {
            float cmax = -3.0e38f;
            for (int sl = lane; sl < cnt; sl += 64) cmax = fmaxf(cmax, l_log[w][sl]);
            for (int off = 32; off; off >>= 1) cmax = fmaxf(cmax, __shfl_xor(cmax, off));
            float csum = 0.f;
            for (int sl = lane; sl < cnt; sl += 64) {
                float p = __expf(l_log[w][sl] - cmax);
                l_log[w][sl] = p;
                csum += p;
            }
            for (int off = 32; off; off >>= 1) csum += __shfl_xor(csum, off);
            float mo = m_run[w];
            float mn = fmaxf(mo, cmax);
            float sc = __expf(mo - mn);
            float fc = __expf(cmax - mn);
            if (lane == 0) {
                s_run[w] = s_run[w] * sc + fc * csum;
                m_run[w] = mn;
                chunk_sc[w] = sc;
            }
            for (int sl = lane; sl < cnt; sl += 64) l_log[w][sl] *= fc;
        }
        __syncthreads();

        // ---- phase C: weighted gather ----
        {
            float scw = chunk_sc[hl];
            for (int q = 0; q < 8; ++q) acc[q] *= scw;
        }
        for (int slot = w; slot < cnt; slot += 4) {
            int gs = start + slot;
            int src;
            if (gs == 0) src = i;
            else {
                int pk = csr_pack[e0 + gs - 1];
                src = pk & 0xFFFF; if (src >= N_NODES) src = 0;
            }
            uint4 xu = xl4[(size_t)src * 64 + lane];
            float p = l_log[hl][slot];
            float xv[8];
            unpack2(xu.x, xv[0], xv[1]); unpack2(xu.y, xv[2], xv[3]);
            unpack2(xu.z, xv[4], xv[5]); unpack2(xu.w, xv[6], xv[7]);
            for (int q = 0; q < 8; ++q) acc[q] += p * xv[q];
        }
    }

    // combine 4 wave partials + normalize + head-mean + bias
    __syncthreads();
    for (int q = 0; q < 8; ++q) l_acc[w][lane * 8 + q] = acc[q];
    __syncthreads();
    if (t < F_DIM) {
        int c = t;
        float v = 0.f;
        for (int h = 0; h < N_HEAD; ++h) {
            float a = l_acc[0][h * F_DIM + c] + l_acc[1][h * F_DIM + c]
                    + l_acc[2][h * F_DIM + c] + l_acc[3][h * F_DIM + c];
            v += a / s_run[h];
        }
        v = v * 0.25f + loadIn(bias, bias_off + c, f32);
        size_t o = (size_t)i * F_DIM + c;
        if (final_layer && f32) ((float*)hout)[o] = v;
        else                    ((unsigned short*)hout)[o] = f2bf(v);
    }
}

// ---------------- launch ----------------

extern "C" void kernel_launch(void* const* d_in, const int* in_sizes, int n_in,
                              void* d_out, int out_size, void* d_ws, size_t ws_size,
                              hipStream_t stream) {
    const void* x          = d_in[0];
    const int*  edge_index = (const int*)d_in[1];
    const void* relations  = d_in[2];
    const int*  rel_index  = (const int*)d_in[3];
    const void* Wl         = d_in[4];
    const void* bl         = d_in[5];
    const void* Wr         = d_in[6];
    const void* br         = d_in[7];
    const void* We         = d_in[8];
    const void* att        = d_in[9];
    const void* bias       = d_in[10];

    char* ws = (char*)d_ws;
    size_t off = 0;
    auto alloc = [&](size_t bytes) -> void* {
        void* p = ws + off;
        off = (off + bytes + 255) & ~(size_t)255;
        return p;
    };
    int*            flag     = (int*)alloc(4);
    int*            deg      = (int*)alloc(N_NODES * 4);
    int*            row_start= (int*)alloc((N_NODES + 1) * 4);
    int*            cursor   = (int*)alloc(N_NODES * 4);
    int*            rcount   = (int*)alloc(N_REL * 4);
    float*          ea_mean  = (float*)alloc(F_DIM * 4);
    int*            csr_pack = (int*)alloc(N_EDGES * 4);
    unsigned short* rel_ext  = (unsigned short*)alloc((size_t)REL_EXT_ROWS * F_DIM * 2);
    unsigned short* Wt       = (unsigned short*)alloc((size_t)12 * HC * F_DIM * 2);  // 1.57 MB
    unsigned short* re       = (unsigned short*)alloc((size_t)REL_EXT_ROWS * HC * 2);
    unsigned short* hbuf     = (unsigned short*)alloc((size_t)N_NODES * F_DIM * 2);
    unsigned short* xl       = (unsigned short*)alloc((size_t)N_NODES * HC * 2);
    unsigned short* xr       = (unsigned short*)alloc((size_t)N_NODES * HC * 2);
    // total ~49 MB

    const int* esrc = edge_index;
    const int* edst = edge_index + N_EDGES;

    detect_kernel<<<1, 64, 0, stream>>>((const unsigned short*)x, flag);
    hipMemsetAsync(rcount, 0, N_REL * 4, stream);
    hipMemsetAsync(deg, 0, N_NODES * 4, stream);
    hipMemsetAsync(ea_mean, 0, F_DIM * 4, stream);
    hist_kernel<<<(N_EDGES + 255) / 256, 256, 0, stream>>>(edst, rel_index, deg, rcount);
    ea_mean_kernel<<<N_REL / 8, 256, 0, stream>>>(rcount, relations, ea_mean, flag);
    relext_kernel<<<(REL_EXT_ROWS * F_DIM + 255) / 256, 256, 0, stream>>>(relations, ea_mean, rel_ext, flag);
    scan_kernel<<<1, 1024, 0, stream>>>(deg, row_start, cursor);
    scatter_kernel<<<(N_EDGES + 255) / 256, 256, 0, stream>>>(esrc, edst, rel_index, cursor, csr_pack);
    w_transpose_kernel<<<dim3(2, 8, 12), 256, 0, stream>>>(Wl, Wr, We, Wt, flag);
    tail_kernel<<<(N_REL * F_DIM + 255) / 256, 256, 0, stream>>>(relations, d_out, flag);

    const void* hin = x;
    int a_input = 1;
    for (int l = 0; l < N_LAYERS; ++l) {
        const unsigned short* Wlt = Wt + (size_t)l * HC * F_DIM;
        const unsigned short* Wrt = Wt + (size_t)(4 + l) * HC * F_DIM;
        const unsigned short* Wet = Wt + (size_t)(8 + l) * HC * F_DIM;
        proj_kernel<<<dim3((N_NODES + 63) / 64, 4), 256, 0, stream>>>(
            hin, a_input, N_NODES, Wlt, Wrt,
            bl, (size_t)l * HC, br, (size_t)l * HC,
            xl, xr, 2, flag);
        proj_kernel<<<dim3((REL_EXT_ROWS + 63) / 64, 4), 256, 0, stream>>>(
            rel_ext, 0, REL_EXT_ROWS, Wet, nullptr,
            nullptr, 0, nullptr, 0,
            re, nullptr, 1, flag);
        int final_layer = (l == N_LAYERS - 1);
        void* hout = final_layer ? d_out : (void*)hbuf;
        edge_kernel<<<N_NODES, 256, 0, stream>>>((const unsigned int*)xl, (const unsigned int*)xr,
                                                 (const unsigned int*)re, row_start, csr_pack,
                                                 att, (size_t)l * N_HEAD * F_DIM,
                                                 bias, (size_t)l * F_DIM,
                                                 hout, final_layer, flag);
        hin = hbuf;
        a_input = 0;
    }
}